// Round 10
// baseline (492.937 us; speedup 1.0000x reference)
//
#include <hip/hip_runtime.h>

#define VIN  16000
#define V1q  16384
#define V2q  4096
#define Kq   16
#define FCIN 65536

typedef unsigned short u16;
typedef unsigned int u32;
typedef unsigned long long u64;
typedef __attribute__((ext_vector_type(8))) short short8;
typedef __attribute__((ext_vector_type(4))) float f32x4;
typedef __attribute__((ext_vector_type(4))) u32 u32x4;

__device__ __forceinline__ float bf2f(u16 v) { return __uint_as_float((unsigned)v << 16); }
__device__ __forceinline__ float bflo(u32 u) { return __uint_as_float(u << 16); }
__device__ __forceinline__ float bfhi(u32 u) { return __uint_as_float(u & 0xffff0000u); }
__device__ __forceinline__ u16 f2bf(float f) {
    unsigned u = __float_as_uint(f);
    return (u16)((u + 0x7fffu + ((u >> 16) & 1u)) >> 16);
}
__device__ __forceinline__ u32 packbf(float a, float b) {
    return (u32)f2bf(a) | ((u32)f2bf(b) << 16);
}

// ---------------- workspace zero (X0 level incl. pad rows) ----------------
__global__ void zero_ws(u16* __restrict__ X0) {
    size_t idx = (size_t)blockIdx.x * 256 + threadIdx.x;   // 2048*256 = 524288
    float4 z = {0.f, 0.f, 0.f, 0.f};
    *(float4*)(X0 + idx * 8) = z;
}

// ---------------- BatchNorm stats (two stage) ----------------
__global__ void bn_part(const float* __restrict__ x, float* __restrict__ part) {
    int c  = blockIdx.y;
    int bx = blockIdx.x;           // 0..63
    int b  = bx >> 2;
    int vc = bx & 3;
    const float* p = x + (size_t)(b * 16 + c) * VIN + vc * 4000;
    float s = 0.f, s2 = 0.f;
    for (int v = threadIdx.x; v < 4000; v += 256) {
        float val = p[v];
        s += val; s2 += val * val;
    }
    for (int o = 32; o; o >>= 1) { s += __shfl_down(s, o); s2 += __shfl_down(s2, o); }
    __shared__ float ls[4], ls2[4];
    int wid = threadIdx.x >> 6;
    if ((threadIdx.x & 63) == 0) { ls[wid] = s; ls2[wid] = s2; }
    __syncthreads();
    if (threadIdx.x == 0) {
        s = ls[0] + ls[1] + ls[2] + ls[3];
        s2 = ls2[0] + ls2[1] + ls2[2] + ls2[3];
        part[(c * 64 + bx) * 2]     = s;
        part[(c * 64 + bx) * 2 + 1] = s2;
    }
}

__global__ void bn_final(const float* __restrict__ part, float* __restrict__ mean_rstd) {
    int t = threadIdx.x;
    int c = t >> 4, j = t & 15;
    float s = 0.f, s2 = 0.f;
    for (int i = 0; i < 4; i++) {
        s  += part[(c * 64 + j * 4 + i) * 2];
        s2 += part[(c * 64 + j * 4 + i) * 2 + 1];
    }
    for (int o = 8; o; o >>= 1) { s += __shfl_down(s, o, 16); s2 += __shfl_down(s2, o, 16); }
    if (j == 0) {
        float m  = s / 256000.f;
        float var = s2 / 256000.f - m * m;
        mean_rstd[c]      = m;
        mean_rstd[16 + c] = rsqrtf(var + 1e-5f);
    }
}

// ---------------- inverse permutation, u16 index pack ----------------
__global__ void build_iperm(const int* __restrict__ perm, int* __restrict__ iperm) {
    int v = blockIdx.x * 256 + threadIdx.x;
    if (v < V1q) iperm[perm[v]] = v;
}
__global__ void build_idx16(const int* __restrict__ c, u16* __restrict__ o, int n) {
    int i = blockIdx.x * 256 + threadIdx.x;
    if (i < n) o[i] = (u16)c[i];
}

// ------- normalize + transpose + permute scatter, bf16, PANEL-major fragment order -------
// value (b,c) -> fragment col' = (c>>3)*128 + b*8 + (c&7); X0p[col'>>2][v][col'&3]
__global__ void norm_transpose_scatter(const float* __restrict__ x,
                                       const float* __restrict__ mean_rstd,
                                       const int* __restrict__ iperm,
                                       u16* __restrict__ X0) {
    __shared__ u16 tile[256][33];
    int u0 = blockIdx.x * 32;
    int t  = threadIdx.x;
    int jj = t & 31, half = t >> 5;
    for (int rr = 0; rr < 32; rr++) {
        int s = rr * 8 + half;           // source row = b*16 + c
        int c = s & 15, b = s >> 4;
        float val = x[(size_t)s * VIN + u0 + jj];
        val = (val - mean_rstd[c]) * mean_rstd[16 + c];
        int d = ((c >> 3) << 7) | (b << 3) | (c & 7);
        tile[d][jj] = f2bf(val);
    }
    __syncthreads();
    size_t pbase = (size_t)(t >> 2) * (V1q * 4) + (t & 3);
    for (int j = 0; j < 32; j++) {
        int tv = iperm[u0 + j];
        X0[pbase + (size_t)tv * 4] = tile[t][j];
    }
}

// ---------------- weight packing into MFMA B-fragment order ----------------
__global__ void pack_w1(const float* __restrict__ w1, u16* __restrict__ B1p) {
    int i = blockIdx.x * 256 + threadIdx.x;   // 8192
    int j = i & 7, l = (i >> 3) & 63, nf = (i >> 9) & 1, s = i >> 10;
    int q = l >> 4;
    int k = s * 2 + (q >> 1);
    int c = (q & 1) * 8 + j;
    int f = nf * 16 + (l & 15);
    B1p[i] = f2bf(w1[f * 256 + c * 16 + k]);
}
__global__ void pack_w2(const float* __restrict__ w2, u16* __restrict__ B2p) {
    int i = blockIdx.x * 256 + threadIdx.x;   // 32768
    int j = i & 7, l = (i >> 3) & 63, nf = (i >> 9) & 3, k = i >> 11;
    int f1 = (l >> 4) * 8 + j;
    int f2 = nf * 16 + (l & 15);
    B2p[i] = f2bf(w2[f2 * 512 + f1 * 16 + k]);
}

// ------- pack P2f fp32 -> bf16 A-fragment order for FC MFMA -------
__global__ void pack_p(const float* __restrict__ P2f, u16* __restrict__ Pp) {
    int i = blockIdx.x * 256 + threadIdx.x;   // 131072
    int l = i & 63, ks = i >> 6;
    int b = l & 15, q = l >> 4;
    const float* src = P2f + (size_t)b * FCIN + ks * 32 + q * 8;
    float4 a0 = *(const float4*)(src);
    float4 a1 = *(const float4*)(src + 4);
    short8 v;
    v[0] = (short)f2bf(a0.x); v[1] = (short)f2bf(a0.y);
    v[2] = (short)f2bf(a0.z); v[3] = (short)f2bf(a0.w);
    v[4] = (short)f2bf(a1.x); v[5] = (short)f2bf(a1.y);
    v[6] = (short)f2bf(a1.z); v[7] = (short)f2bf(a1.w);
    *(short8*)(Pp + (size_t)i * 8) = v;
}

// ---------------- Chebyshev SpMM: panel in LDS, gathers from LDS ----------------
// panel = 4 cols (8B/row). Block (panel, row-split): stage prev's panel (V*8B) in LDS,
// then per-thread rows: 16 ds_read_b64 gathers + FMA. Data panel-major: [k][p][V][4].
template<int V, int NT, int RPT, int RSPLIT>
__launch_bounds__(NT)
__global__ void spmm_lds(const u16* __restrict__ prev, const u16* __restrict__ prev2,
                         u16* __restrict__ out,
                         const u16* __restrict__ idx16, const float* __restrict__ vals,
                         float scale, int sub) {
    __shared__ __align__(16) u16 srcs[V * 4];
    int t = threadIdx.x;
    int p  = blockIdx.x / RSPLIT;
    int rg = blockIdx.x % RSPLIT;
    // stage panel p of prev (contiguous V*8 bytes)
    {
        const u32x4* g4 = (const u32x4*)(prev + (size_t)p * V * 4);
        u32x4* s4 = (u32x4*)srcs;
        constexpr int NI = (V / 2) / NT;
#pragma unroll
        for (int i = 0; i < NI; i++) s4[i * NT + t] = g4[i * NT + t];
    }
    __syncthreads();
    const u64* s64 = (const u64*)srcs;
    const u64* p2_64 = (const u64*)(prev2 + (size_t)p * V * 4);
    u64* o64 = (u64*)(out + (size_t)p * V * 4);
    int row0 = rg * (V / RSPLIT);
#pragma unroll
    for (int i = 0; i < RPT; i++) {
        int row = row0 + i * NT + t;
        const int4* ip = (const int4*)(idx16 + (size_t)row * 16);
        int4 ia = ip[0], ib = ip[1];
        const float4* vp = (const float4*)(vals + (size_t)row * 16);
        float4 va = vp[0], vb = vp[1], vc = vp[2], vd = vp[3];
        u32 w[8] = {(u32)ia.x, (u32)ia.y, (u32)ia.z, (u32)ia.w,
                    (u32)ib.x, (u32)ib.y, (u32)ib.z, (u32)ib.w};
        float vv[16] = {va.x, va.y, va.z, va.w, vb.x, vb.y, vb.z, vb.w,
                        vc.x, vc.y, vc.z, vc.w, vd.x, vd.y, vd.z, vd.w};
        u64 g[16];
#pragma unroll
        for (int j = 0; j < 16; j++) {
            u32 id = (j & 1) ? (w[j >> 1] >> 16) : (w[j >> 1] & 0xffffu);
            g[j] = s64[id];
        }
        float a0 = 0.f, a1 = 0.f, a2 = 0.f, a3 = 0.f;
#pragma unroll
        for (int j = 0; j < 16; j++) {
            u32 lo = (u32)g[j], hi = (u32)(g[j] >> 32);
            float v = vv[j];
            a0 += v * bflo(lo); a1 += v * bfhi(lo);
            a2 += v * bflo(hi); a3 += v * bfhi(hi);
        }
        float o0 = scale * a0, o1 = scale * a1, o2 = scale * a2, o3 = scale * a3;
        if (sub) {
            u64 q = __builtin_nontemporal_load(p2_64 + row);
            u32 lo = (u32)q, hi = (u32)(q >> 32);
            o0 -= bflo(lo); o1 -= bfhi(lo); o2 -= bflo(hi); o3 -= bfhi(hi);
        }
        u64 pk = (u64)packbf(o0, o1) | ((u64)packbf(o2, o3) << 32);
        o64[row] = pk;
    }
}

// ------- GEMM1 (MFMA): panel-major A, relu+pool4 -> XS2 slice0 (panel-major) -------
__launch_bounds__(256)
__global__ void gemm1_mfma(const u16* __restrict__ XS1, const u16* __restrict__ B1p,
                           const float* __restrict__ b1, u16* __restrict__ XS2_0) {
    __shared__ __align__(16) u16 As[2][4096];   // row-major [slice(2)][8 rows][256 cols]
    int t = threadIdx.x;
    int w = t >> 6, l = t & 63;
    int v0 = blockIdx.x * 8;
    int nf = w & 1, vq = w >> 1;
    const u64* X64 = (const u64*)XS1;
    u64* A64 = (u64*)As;

    f32x4 acc[4] = {};
    // stage slices k0, k0+1 into As[buf]
    auto stage = [&](int buf, int k0) {
#pragma unroll
        for (int q = 0; q < 4; q++) {
            int c = t + 256 * q;
            int sl = c >> 9, cc = c & 511;
            int row = cc & 7, panel = cc >> 3;
            A64[buf * 1024 + sl * 512 + row * 64 + panel] =
                X64[(size_t)(k0 + sl) * 1048576 + (size_t)panel * 16384 + v0 + row];
        }
    };
    stage(0, 0);
    __syncthreads();
    for (int s = 0; s < 8; s++) {
        int cur = s & 1;
        if (s < 7) stage(cur ^ 1, 2 * s + 2);
        short8 bfrag = *(const short8*)(B1p + (((size_t)s * 2 + nf) * 64 + l) * 8);
        int abase = (l >> 5) * 2048 + (l & 31) * 8;
#pragma unroll
        for (int fm = 0; fm < 4; fm++) {
            int vl = vq * 4 + fm;
            short8 afrag = *(const short8*)&As[cur][abase + vl * 256];
            acc[fm] = __builtin_amdgcn_mfma_f32_16x16x32_bf16(afrag, bfrag, acc[fm], 0, 0, 0);
        }
        __syncthreads();
    }
    f32x4 m = acc[0];
#pragma unroll
    for (int fm = 1; fm < 4; fm++) {
#pragma unroll
        for (int i = 0; i < 4; i++) m[i] = fmaxf(m[i], acc[fm][i]);
    }
    int f1 = nf * 16 + (l & 15);
    float bias = b1[f1];
    int u_out = blockIdx.x * 2 + vq;
    int colbase = ((f1 >> 3) << 7) | (f1 & 7);
#pragma unroll
    for (int reg = 0; reg < 4; reg++) {
        int b = (l >> 4) * 4 + reg;
        int cc = colbase + b * 8;
        XS2_0[(size_t)(cc >> 2) * (V2q * 4) + (size_t)u_out * 4 + (cc & 3)] =
            f2bf(fmaxf(m[reg] + bias, 0.f));
    }
}

// ------- GEMM2 (MFMA): panel-major A, relu+pool4 -> P2f fp32 -------
__launch_bounds__(256)
__global__ void gemm2_mfma(const u16* __restrict__ XS2, const u16* __restrict__ B2p,
                           const float* __restrict__ b2, float* __restrict__ P2f) {
    __shared__ __align__(16) u16 As[2][8192];   // row-major [16 rows][512 cols]
    __shared__ float ylds[4 * 16 * 66];
    int t = threadIdx.x;
    int w = t >> 6, l = t & 63;
    int u0 = blockIdx.x * 16;
    const u64* X64 = (const u64*)XS2;
    u64* A64 = (u64*)As;

    f32x4 acc[4][4] = {};
    auto stage = [&](int buf, int k0) {
#pragma unroll
        for (int q = 0; q < 8; q++) {
            int c = t + 256 * q;
            int row = c & 15, panel = c >> 4;
            A64[buf * 2048 + row * 128 + panel] =
                X64[(size_t)k0 * 524288 + (size_t)panel * 4096 + u0 + row];
        }
    };
    stage(0, 0);
    __syncthreads();
    for (int k = 0; k < 16; k++) {
        int cur = k & 1;
        if (k < 15) stage(cur ^ 1, k + 1);
        short8 bfrag[4];
#pragma unroll
        for (int nf = 0; nf < 4; nf++)
            bfrag[nf] = *(const short8*)(B2p + (((size_t)k * 4 + nf) * 64 + l) * 8);
#pragma unroll
        for (int fm = 0; fm < 4; fm++) {
            int ul = w * 4 + fm;
            short8 afrag = *(const short8*)&As[cur][ul * 512 + l * 8];
#pragma unroll
            for (int nf = 0; nf < 4; nf++)
                acc[fm][nf] = __builtin_amdgcn_mfma_f32_16x16x32_bf16(afrag, bfrag[nf], acc[fm][nf], 0, 0, 0);
        }
        __syncthreads();
    }
#pragma unroll
    for (int nf = 0; nf < 4; nf++) {
        int f2 = nf * 16 + (l & 15);
        float bias = b2[f2];
#pragma unroll
        for (int reg = 0; reg < 4; reg++) {
            int b = (l >> 4) * 4 + reg;
            float m = fmaxf(fmaxf(acc[0][nf][reg], acc[1][nf][reg]),
                            fmaxf(acc[2][nf][reg], acc[3][nf][reg]));
            ylds[(w * 16 + b) * 66 + f2] = fmaxf(m + bias, 0.f);
        }
    }
    __syncthreads();
    int ub = blockIdx.x * 4;
#pragma unroll
    for (int i = 0; i < 4; i++) {
        int p = t + i * 256;
        int b = p >> 6, f2 = p & 63;
        float4 v;
        v.x = ylds[(0 * 16 + b) * 66 + f2];
        v.y = ylds[(1 * 16 + b) * 66 + f2];
        v.z = ylds[(2 * 16 + b) * 66 + f2];
        v.w = ylds[(3 * 16 + b) * 66 + f2];
        *(float4*)&P2f[(size_t)(b * 64 + f2) * 1024 + ub] = v;
    }
}

// ---------------- FC ----------------
__global__ void fc_init(const float* __restrict__ b, float* __restrict__ out) {
    int i = blockIdx.x * 256 + threadIdx.x;   // 8192
    out[i] = b[i & 511];
}

__launch_bounds__(256)
__global__ void fc_mfma(const u16* __restrict__ Pp, const float* __restrict__ W,
                        float* __restrict__ out) {
    int t = threadIdx.x;
    int w = t >> 6, l = t & 63;
    int n0 = blockIdx.x * 16;
    int ks0 = blockIdx.y * 64 + w * 16;
    int o = n0 + (l & 15);
    const float* wp = W + (size_t)o * FCIN + (size_t)ks0 * 32 + (l >> 4) * 8;
    const u16*   ap = Pp + ((size_t)ks0 * 64 + l) * 8;
    f32x4 acc = {};
    for (int s = 0; s < 16; s++) {
        short8 afrag = *(const short8*)(ap + (size_t)s * 512);
        float4 w0 = *(const float4*)(wp + s * 32);
        float4 w1 = *(const float4*)(wp + s * 32 + 4);
        short8 bfrag;
        bfrag[0] = (short)f2bf(w0.x); bfrag[1] = (short)f2bf(w0.y);
        bfrag[2] = (short)f2bf(w0.z); bfrag[3] = (short)f2bf(w0.w);
        bfrag[4] = (short)f2bf(w1.x); bfrag[5] = (short)f2bf(w1.y);
        bfrag[6] = (short)f2bf(w1.z); bfrag[7] = (short)f2bf(w1.w);
        acc = __builtin_amdgcn_mfma_f32_16x16x32_bf16(afrag, bfrag, acc, 0, 0, 0);
    }
    __shared__ float red[4][256];
#pragma unroll
    for (int r = 0; r < 4; r++)
        red[w][((l >> 4) * 4 + r) * 16 + (l & 15)] = acc[r];
    __syncthreads();
    float s = red[0][t] + red[1][t] + red[2][t] + red[3][t];
    atomicAdd(&out[(t >> 4) * 512 + n0 + (t & 15)], s);
}

extern "C" void kernel_launch(void* const* d_in, const int* in_sizes, int n_in,
                              void* d_out, int out_size, void* d_ws, size_t ws_size,
                              hipStream_t stream) {
    const float* x       = (const float*)d_in[0];
    const int*   perm    = (const int*)d_in[1];
    const int*   l1_cols = (const int*)d_in[3];
    const float* l1_vals = (const float*)d_in[4];
    const int*   l2_cols = (const int*)d_in[6];
    const float* l2_vals = (const float*)d_in[7];
    const float* w1      = (const float*)d_in[8];
    const float* b1      = (const float*)d_in[9];
    const float* w2      = (const float*)d_in[10];
    const float* b2      = (const float*)d_in[11];
    const float* fcw     = (const float*)d_in[12];
    const float* fcb     = (const float*)d_in[13];
    float* out = (float*)d_out;

    char* wsb = (char*)d_ws;
    size_t off = 0;
    auto alloc = [&](size_t bytes) -> void* {
        void* p = wsb + off;
        off += (bytes + 255) & ~(size_t)255;
        return p;
    };
    float* mean_rstd = (float*)alloc(32 * 4);
    float* bnpart    = (float*)alloc(16 * 64 * 2 * 4);
    int*   iperm     = (int*)alloc((size_t)V1q * 4);
    u16*   idx1      = (u16*)alloc((size_t)V1q * 16 * 2);
    u16*   idx2      = (u16*)alloc((size_t)V2q * 16 * 2);
    u16*   B1p       = (u16*)alloc(8192 * 2);
    u16*   B2p       = (u16*)alloc(32768 * 2);
    u16*   XS1       = (u16*)alloc((size_t)Kq * V1q * 256 * 2);   // panel-major [k][64][V1][4]
    u16*   XS2       = (u16*)alloc((size_t)Kq * V2q * 512 * 2);   // panel-major [k][128][V2][4]
    float* P2f       = (float*)alloc((size_t)16 * FCIN * 4);
    u16*   Pp        = (u16*)alloc((size_t)16 * FCIN * 2);
    (void)ws_size; (void)in_sizes; (void)n_in; (void)out_size;

    const size_t S1 = (size_t)V1q * 256;
    const size_t S2 = (size_t)V2q * 512;

    zero_ws<<<2048, 256, 0, stream>>>(XS1);
    bn_part<<<dim3(64, 16), 256, 0, stream>>>(x, bnpart);
    bn_final<<<1, 256, 0, stream>>>(bnpart, mean_rstd);
    build_iperm<<<V1q / 256, 256, 0, stream>>>(perm, iperm);
    build_idx16<<<V1q * 16 / 256, 256, 0, stream>>>(l1_cols, idx1, V1q * 16);
    build_idx16<<<V2q * 16 / 256, 256, 0, stream>>>(l2_cols, idx2, V2q * 16);
    norm_transpose_scatter<<<500, 256, 0, stream>>>(x, mean_rstd, iperm, XS1);
    pack_w1<<<32, 256, 0, stream>>>(w1, B1p);
    pack_w2<<<128, 256, 0, stream>>>(w2, B2p);

    // Chebyshev levels, conv1: 64 panels x 4 row-splits, 1024-thread blocks, 128KB LDS
    spmm_lds<V1q, 1024, 4, 4><<<256, 1024, 0, stream>>>(XS1, XS1, XS1 + S1, idx1, l1_vals, 1.f, 0);
    for (int k = 2; k < Kq; k++)
        spmm_lds<V1q, 1024, 4, 4><<<256, 1024, 0, stream>>>(XS1 + (size_t)(k - 1) * S1, XS1 + (size_t)(k - 2) * S1,
                                                            XS1 + (size_t)k * S1, idx1, l1_vals, 2.f, 1);
    gemm1_mfma<<<V1q / 8, 256, 0, stream>>>(XS1, B1p, b1, XS2);

    // Chebyshev levels, conv2: 128 panels x 4 row-splits, 256-thread blocks, 32KB LDS
    spmm_lds<V2q, 256, 4, 4><<<512, 256, 0, stream>>>(XS2, XS2, XS2 + S2, idx2, l2_vals, 1.f, 0);
    for (int k = 2; k < Kq; k++)
        spmm_lds<V2q, 256, 4, 4><<<512, 256, 0, stream>>>(XS2 + (size_t)(k - 1) * S2, XS2 + (size_t)(k - 2) * S2,
                                                          XS2 + (size_t)k * S2, idx2, l2_vals, 2.f, 1);
    gemm2_mfma<<<V2q / 16, 256, 0, stream>>>(XS2, B2p, b2, P2f);

    // FC
    pack_p<<<512, 256, 0, stream>>>(P2f, Pp);
    fc_init<<<32, 256, 0, stream>>>(fcb, out);
    fc_mfma<<<dim3(32, 32), 256, 0, stream>>>(Pp, fcw, out);
}